// Round 4
// baseline (58.152 us; speedup 1.0000x reference)
//
#include <hip/hip_runtime.h>
#include <hip/hip_bf16.h>

#define NB 256
#define NK 32
#define NL 4096
#define NC 8            // L-chunks per row
#define CH 512          // chunk length
#define EPSV 1e-5f
#define PEAK_LAMBDA 0.005f
#define ORTHO_LAMBDA 20000.0f
#define LN2F 0.6931471805599453f

typedef __attribute__((ext_vector_type(8))) short short8;
typedef __attribute__((ext_vector_type(4))) float f32x4;

// ---------------- Kernel 1: fused single-pass, no LDS staging ----------------
// grid = NB*NC (b-major), block = 256 (4 waves). Each block covers a 32x512
// chunk of one b. Each lane loads its MFMA fragments (rows lane&15 and
// 16+(lane&15), 8 consecutive floats at (lane>>4)*8) DIRECTLY from global,
// converts fp32->bf16 with v_cvt_pk_bf16_f32, and fuses argmax + sum(log2)
// on the same register data. Main loop: 0 barriers, 0 LDS.
// Gram symmetry: G10 == G01^T, skipped (weighted x2 in k_fin).
__global__ __launch_bounds__(256, 4) void k_main(const float* __restrict__ a,
                                                 float* __restrict__ gram,
                                                 float* __restrict__ rmax,
                                                 int* __restrict__ ridx,
                                                 float* __restrict__ rlogp) {
    const int bc = blockIdx.x;
    const int b = bc >> 3, chk = bc & 7;
    const int tid = threadIdx.x;
    const int lane = tid & 63, wv = tid >> 6;
    const int r0 = lane & 15, hi = lane >> 4;

    // wave wv owns l in [wv*128, wv*128+128) of the chunk: 4 MFMA k-steps
    const float* __restrict__ rowA =
        a + ((size_t)b * NK + r0) * NL + chk * CH + wv * 128 + hi * 8;
    const float* __restrict__ rowB = rowA + 16 * (size_t)NL;
    const int lbase = chk * CH + wv * 128 + hi * 8;

    float mvA = -1.0f, mvB = -1.0f;
    int miA = 0, miB = 0;
    float lpA0 = 0.0f, lpA1 = 0.0f, lpB0 = 0.0f, lpB1 = 0.0f;
    f32x4 acc00 = {0.f,0.f,0.f,0.f}, acc01 = {0.f,0.f,0.f,0.f},
          acc11 = {0.f,0.f,0.f,0.f};

#pragma unroll
    for (int s = 0; s < 4; ++s) {
        float4 a0 = *reinterpret_cast<const float4*>(rowA + s * 32);
        float4 a1 = *reinterpret_cast<const float4*>(rowA + s * 32 + 4);
        float4 b0 = *reinterpret_cast<const float4*>(rowB + s * 32);
        float4 b1 = *reinterpret_cast<const float4*>(rowB + s * 32 + 4);
        float va[8] = {a0.x, a0.y, a0.z, a0.w, a1.x, a1.y, a1.z, a1.w};
        float vb[8] = {b0.x, b0.y, b0.z, b0.w, b1.x, b1.y, b1.z, b1.w};
        const int l0 = lbase + s * 32;
        union { unsigned u[4]; short8 s8; } fa, fb;
#pragma unroll
        for (int c2 = 0; c2 < 4; ++c2) {
            // element pair 2*c2, 2*c2+1; p = a + eps computed ONCE,
            // reused by log2 accumulation and bf16 convert
            float xa0 = va[2*c2]     + EPSV;
            float xa1 = va[2*c2 + 1] + EPSV;
            float xb0 = vb[2*c2]     + EPSV;
            float xb1 = vb[2*c2 + 1] + EPSV;
            if (va[2*c2]     > mvA) { mvA = va[2*c2];     miA = l0 + 2*c2; }
            if (va[2*c2 + 1] > mvA) { mvA = va[2*c2 + 1]; miA = l0 + 2*c2 + 1; }
            if (vb[2*c2]     > mvB) { mvB = vb[2*c2];     miB = l0 + 2*c2; }
            if (vb[2*c2 + 1] > mvB) { mvB = vb[2*c2 + 1]; miB = l0 + 2*c2 + 1; }
            lpA0 += __log2f(xa0); lpA1 += __log2f(xa1);
            lpB0 += __log2f(xb0); lpB1 += __log2f(xb1);
            asm("v_cvt_pk_bf16_f32 %0, %1, %2"
                : "=v"(fa.u[c2]) : "v"(xa0), "v"(xa1));
            asm("v_cvt_pk_bf16_f32 %0, %1, %2"
                : "=v"(fb.u[c2]) : "v"(xb0), "v"(xb1));
        }
        acc00 = __builtin_amdgcn_mfma_f32_16x16x32_bf16(fa.s8, fa.s8, acc00, 0, 0, 0);
        acc01 = __builtin_amdgcn_mfma_f32_16x16x32_bf16(fa.s8, fb.s8, acc01, 0, 0, 0);
        acc11 = __builtin_amdgcn_mfma_f32_16x16x32_bf16(fb.s8, fb.s8, acc11, 0, 0, 0);
    }
    float lpA = (lpA0 + lpA1) * LN2F;
    float lpB = (lpB0 + lpB1) * LN2F;

    // ---- cross-lane per-row reduce: row r0 lives in lanes {r0,+16,+32,+48}
#pragma unroll
    for (int off = 16; off <= 32; off <<= 1) {
        float ov = __shfl_xor(mvA, off); int oi = __shfl_xor(miA, off);
        if (ov > mvA || (ov == mvA && oi < miA)) { mvA = ov; miA = oi; }
        ov = __shfl_xor(mvB, off); oi = __shfl_xor(miB, off);
        if (ov > mvB || (ov == mvB && oi < miB)) { mvB = ov; miB = oi; }
        lpA += __shfl_xor(lpA, off);
        lpB += __shfl_xor(lpB, off);
    }

    __shared__ float s_mv[4][32], s_lp[4][32];
    __shared__ int   s_mi[4][32];
    __shared__ float gbuf[4][768];

    if (hi == 0) {
        s_mv[wv][r0] = mvA; s_mi[wv][r0] = miA; s_lp[wv][r0] = lpA;
        s_mv[wv][16 + r0] = mvB; s_mi[wv][16 + r0] = miB; s_lp[wv][16 + r0] = lpB;
    }
    // Gram C/D layout (m89-verified): col = lane&15, row = (lane>>4)*4 + reg
    {
        const int rb2 = hi * 4;
#pragma unroll
        for (int r = 0; r < 4; ++r) {
            int gr = rb2 + r;
            gbuf[wv][gr * 16 + r0]       = acc00[r];
            gbuf[wv][256 + gr * 16 + r0] = acc01[r];
            gbuf[wv][512 + gr * 16 + r0] = acc11[r];
        }
    }
    __syncthreads();

    if (tid < 32) {  // combine 4 wave partials per row (waves ascending-l)
        float bv = -1.0f, lp = 0.0f; int bi = 0;
#pragma unroll
        for (int w = 0; w < 4; ++w) {
            float v = s_mv[w][tid]; int i = s_mi[w][tid];
            if (v > bv || (v == bv && i < bi)) { bv = v; bi = i; }
            lp += s_lp[w][tid];
        }
        rmax[bc * 32 + tid] = bv;
        ridx[bc * 32 + tid] = bi;
        rlogp[bc * 32 + tid] = lp;
    }
#pragma unroll
    for (int j = 0; j < 3; ++j) {
        int e = tid + 256 * j;
        gram[(size_t)bc * 768 + e] =
            gbuf[0][e] + gbuf[1][e] + gbuf[2][e] + gbuf[3][e];
    }
}

// ---------------- Kernel 2: per-b finalize ----------------
// Combines chunk partials; exact KL via the 64-wide Gaussian window
// (g underflows to 0 for |d|>=22 in fp32); off-diag Gram^2 with G01 weight 2.
__global__ __launch_bounds__(256) void k_fin(const float* __restrict__ a,
                                             const float* __restrict__ gram,
                                             const float* __restrict__ rmax,
                                             const int* __restrict__ ridx,
                                             const float* __restrict__ rlogp,
                                             float* __restrict__ bpeak,
                                             float* __restrict__ bortho) {
    const int b = blockIdx.x;
    const int tid = threadIdx.x;
    __shared__ int idx_s[32];
    __shared__ float lp_s[32];
    __shared__ float rkl_s[32];
    __shared__ float red[256];

    // ortho: sum NC chunk Grams then square. blocks: [0]=G00 [1]=G01 [2]=G11
    float local = 0.0f;
#pragma unroll
    for (int j = 0; j < 3; ++j) {
        int e = tid + 256 * j;
        float s = 0.0f;
#pragma unroll
        for (int ch = 0; ch < NC; ++ch)
            s += gram[(size_t)(b * NC + ch) * 768 + e];
        int blk = e >> 8, idx = e & 255, k = idx >> 4, m = idx & 15;
        float w = (blk == 1) ? 2.0f : ((k == m) ? 0.0f : 1.0f);
        local += w * s * s;
    }

    // combine per-row chunk partials (chunks ascending-l; idx tiebreak)
    if (tid < 32) {
        float bv = -1.0f; int bi = 0; float lp = 0.0f;
#pragma unroll
        for (int ch = 0; ch < NC; ++ch) {
            float v = rmax[(b * NC + ch) * 32 + tid];
            int i = ridx[(b * NC + ch) * 32 + tid];
            if (v > bv || (v == bv && i < bi)) { bv = v; bi = i; }
            lp += rlogp[(b * NC + ch) * 32 + tid];
        }
        idx_s[tid] = bi; lp_s[tid] = lp;
    }
    __syncthreads();

    // window: 8 threads per row, 8 positions each, l = idx-31 .. idx+32
    const int r = tid >> 3, cc = tid & 7;
    const int idx = idx_s[r];
    const float* __restrict__ arow = a + ((size_t)b * 32 + r) * (size_t)NL;
    float gv[8], pvv[8];
    float zs = 0.0f;
#pragma unroll
    for (int w = 0; w < 8; ++w) {
        int l = idx - 31 + cc + 8 * w;
        float d = (float)(cc + 8 * w - 31);
        float g = __expf(d * d * (-1.0f / 4.5f));
        if (l >= 0 && l < NL) { gv[w] = g; zs += g; pvv[w] = arow[l]; }
        else { gv[w] = 0.0f; pvv[w] = 1.0f; }
    }
    zs += __shfl_xor(zs, 1); zs += __shfl_xor(zs, 2); zs += __shfl_xor(zs, 4);
    const float rz = 1.0f / zs;
    float tlt = 0.0f, tlp = 0.0f;
#pragma unroll
    for (int w = 0; w < 8; ++w) {
        int l = idx - 31 + cc + 8 * w;
        if (l >= 0 && l < NL) {
            float gg = gv[w] * rz;
            float tf = gg + EPSV;
            tlt += tf * __logf(tf);
            tlp += gg * __logf(pvv[w] + EPSV);
        }
    }
    tlt += __shfl_xor(tlt, 1); tlt += __shfl_xor(tlt, 2); tlt += __shfl_xor(tlt, 4);
    tlp += __shfl_xor(tlp, 1); tlp += __shfl_xor(tlp, 2); tlp += __shfl_xor(tlp, 4);
    if (cc == 0) {
        int lo = max(0, idx - 31), hi2 = min(NL - 1, idx + 32);
        int nv = hi2 - lo + 1;
        rkl_s[r] = tlt + (float)(NL - nv) * EPSV * __logf(EPSV)
                 - tlp - EPSV * lp_s[r];
    }
    red[tid] = local;
    __syncthreads();
    for (int s = 128; s > 0; s >>= 1) {
        if (tid < s) red[tid] += red[tid + s];
        __syncthreads();
    }
    if (tid == 0) bortho[b] = red[0];
    __syncthreads();
    red[tid] = (tid < 32) ? rkl_s[tid] : 0.0f;
    __syncthreads();
    for (int s = 128; s > 0; s >>= 1) {
        if (tid < s) red[tid] += red[tid + s];
        __syncthreads();
    }
    if (tid == 0) bpeak[b] = red[0];
}

// ---------------- Kernel 3: final 256 -> scalars ----------------
__global__ __launch_bounds__(256) void k_final(const float* __restrict__ bpeak,
                                               const float* __restrict__ bortho,
                                               float* __restrict__ out) {
    const int tid = threadIdx.x;
    __shared__ float s1[256], s2[256];
    s1[tid] = bpeak[tid];
    s2[tid] = bortho[tid];
    __syncthreads();
    for (int s = 128; s > 0; s >>= 1) {
        if (tid < s) { s1[tid] += s1[tid + s]; s2[tid] += s2[tid + s]; }
        __syncthreads();
    }
    if (tid == 0) {
        float peak = PEAK_LAMBDA * s1[0];
        float ortho = ORTHO_LAMBDA * (s2[0] / (float)(NB * NK * NK));
        out[0] = peak + ortho;
        out[1] = peak;
        out[2] = ortho;
    }
}

extern "C" void kernel_launch(void* const* d_in, const int* in_sizes, int n_in,
                              void* d_out, int out_size, void* d_ws, size_t ws_size,
                              hipStream_t stream) {
    const float* a = (const float*)d_in[0];
    float* out = (float*)d_out;
    float* ws = (float*)d_ws;
    float* gram  = ws;                                   // NB*NC*768 floats
    float* rmax  = gram + (size_t)NB * NC * 768;         // NB*NC*32
    int*   ridxp = (int*)(rmax + NB * NC * 32);
    float* rlogp = (float*)(ridxp + NB * NC * 32);
    float* bpeak = rlogp + NB * NC * 32;                 // 256
    float* bortho = bpeak + NB;                          // 256

    k_main<<<NB * NC, 256, 0, stream>>>(a, gram, rmax, ridxp, rlogp);
    k_fin<<<NB, 256, 0, stream>>>(a, gram, rmax, ridxp, rlogp, bpeak, bortho);
    k_final<<<1, 256, 0, stream>>>(bpeak, bortho, out);
}